// Round 2
// baseline (70217.230 us; speedup 1.0000x reference)
//
#include <hip/hip_runtime.h>
#include <hip/hip_bf16.h>
#include <math.h>

// ---------------- problem constants ----------------
#define BATCH 200
#define T_FEAT 2048
#define F_DIM 128
#define T_CHAR 128
#define EMB_D 150
#define H_FEAT 256
#define H_CHAR 200
#define HID 264
#define NCLS 8

// ---------------- persistent feature-GRU geometry ----------------
#define FBC 8          // batch chunks (barrier groups)
#define FTB 25         // batch rows per block
#define FUC 32         // unit chunks = blocks per group
#define FUJ 8          // h-units per block
#define FD  128
#define FH  256
#define FDH 384        // fused row length D+H
#define WLP 388        // LDS row stride for weight slice (388%32=4 -> banks spread)
#define HLP 260        // LDS row stride for h rows     (260%32=4 -> banks spread)

// ---------------------------------------------------------------------------
// prep: build fused+transposed recurrent weights WT[3H][XPAD+H]
//   row c (= original gate-column index in [0,3H)) holds [ W[0:D,c] | 0 | U[0:H,c] ]
// ---------------------------------------------------------------------------
__global__ void prep_wt(const float* __restrict__ W, const float* __restrict__ U,
                        float* __restrict__ WT, int D, int XPAD, int H)
{
    const int DHp = XPAD + H;
    const int total = 3 * H * DHp;
    int idx = blockIdx.x * blockDim.x + threadIdx.x;
    if (idx >= total) return;
    int c = idx / DHp;
    int d = idx % DHp;
    float v;
    if (d < D)          v = W[(size_t)d * (3 * H) + c];
    else if (d < XPAD)  v = 0.f;
    else                v = U[(size_t)(d - XPAD) * (3 * H) + c];
    WT[idx] = v;
}

// ---------------------------------------------------------------------------
// Persistent feature GRU. One cooperative launch runs all T_FEAT steps.
//   block: 512 threads = 8 waves. waves 0-3: k=0 (x[0:128]+h[0:64]),
//   waves 4-7: k=1 (h[64:256]). pair (b,j) -> batch row bg+b, unit ug+j.
//   Cross-block sync: per-group monotonic counter (32 arrivals / step).
// ---------------------------------------------------------------------------
__launch_bounds__(512)
__global__ void gru_feat_persist(const float* __restrict__ feat,
                                 const float* __restrict__ WT,   // [768][384]
                                 const float* __restrict__ b0,   // [768]
                                 const float* __restrict__ b1,   // [768]
                                 float* __restrict__ hA,         // [B][H] (zeroed)
                                 float* __restrict__ hB,         // [B][H]
                                 unsigned int* __restrict__ ctrs)// [FBC*64] (zeroed)
{
    __shared__ float w[3 * FUJ][WLP];   // 24 x 388 = 37.25 KB
    __shared__ float hl[FTB][HLP];      // 25 x 260 = 26.0 KB

    const int tid = threadIdx.x;
    const int bc  = blockIdx.x & 7;     // barrier group (same XCD if round-robin)
    const int uc  = blockIdx.x >> 3;
    const int bg  = bc * FTB;
    const int ug  = uc * FUJ;

    // ---- stage this block's weight slice once (reused 2048 steps) ----
    for (int i = tid; i < 3 * FUJ * (FDH / 4); i += 512) {
        int r  = i / (FDH / 4);
        int d4 = (i % (FDH / 4)) * 4;
        int wrow = (r / FUJ) * FH + ug + (r % FUJ);     // gate*256 + unit
        *reinterpret_cast<float4*>(&w[r][d4]) =
            *reinterpret_cast<const float4*>(WT + (size_t)wrow * FDH + d4);
    }

    const int k = tid >> 8;             // 0: waves 0-3, 1: waves 4-7
    const int pairIdx = tid & 255;
    const int j = pairIdx & (FUJ - 1);
    const int b = pairIdx >> 3;         // valid < FTB
    const bool valid = (b < FTB);

    // bias combos for this thread's unit
    const float bzz = b0[ug + j] + b1[ug + j];
    const float brr = b0[FH + ug + j] + b1[FH + ug + j];
    const float bxh = b0[2 * FH + ug + j];
    const float brh = b1[2 * FH + ug + j];

    unsigned int* ctr = ctrs + (size_t)bc * 64;   // 256B-spaced counters
    float* pxch = &hl[0][0];                      // partial-sum exchange, aliases hl
    const float* hbuf[2] = { hA, hB };

    for (int t = 0; t < T_FEAT; ++t) {
        const float* hin  = hbuf[t & 1];
        float*       hout = const_cast<float*>(hbuf[(t + 1) & 1]);

        // ---- stage h[bg:bg+25][0:256] into LDS ----
        for (int i = tid; i < FTB * (FH / 4); i += 512) {
            int bb = i >> 6;
            int v  = (i & 63) << 2;
            *reinterpret_cast<float4*>(&hl[bb][v]) =
                *reinterpret_cast<const float4*>(hin + (size_t)(bg + bb) * FH + v);
        }
        __syncthreads();

        // ---- fused dots, K-split across wave halves ----
        float az = 0.f, ar = 0.f, axh = 0.f, aoh = 0.f;
        float hold = 0.f;
        if (valid) {
            const float* wz = w[j];
            const float* wr = w[FUJ + j];
            const float* wh = w[2 * FUJ + j];
            if (k == 0) {
                const float* xg = feat + ((size_t)(bg + b) * T_FEAT + t) * FD;
                #pragma unroll 8
                for (int d = 0; d < FD; d += 4) {
                    float4 xv = *reinterpret_cast<const float4*>(xg + d);
                    float4 a4 = *reinterpret_cast<const float4*>(wz + d);
                    float4 c4 = *reinterpret_cast<const float4*>(wr + d);
                    float4 e4 = *reinterpret_cast<const float4*>(wh + d);
                    az  += xv.x*a4.x + xv.y*a4.y + xv.z*a4.z + xv.w*a4.w;
                    ar  += xv.x*c4.x + xv.y*c4.y + xv.z*c4.z + xv.w*c4.w;
                    axh += xv.x*e4.x + xv.y*e4.y + xv.z*e4.z + xv.w*e4.w;
                }
                #pragma unroll 8
                for (int d = 0; d < 64; d += 4) {
                    float4 hv = *reinterpret_cast<const float4*>(&hl[b][d]);
                    float4 a4 = *reinterpret_cast<const float4*>(wz + FD + d);
                    float4 c4 = *reinterpret_cast<const float4*>(wr + FD + d);
                    float4 e4 = *reinterpret_cast<const float4*>(wh + FD + d);
                    az  += hv.x*a4.x + hv.y*a4.y + hv.z*a4.z + hv.w*a4.w;
                    ar  += hv.x*c4.x + hv.y*c4.y + hv.z*c4.z + hv.w*c4.w;
                    aoh += hv.x*e4.x + hv.y*e4.y + hv.z*e4.z + hv.w*e4.w;
                }
                hold = hl[b][ug + j];      // read BEFORE pxch aliases hl
            } else {
                #pragma unroll 8
                for (int d = 64; d < FH; d += 4) {
                    float4 hv = *reinterpret_cast<const float4*>(&hl[b][d]);
                    float4 a4 = *reinterpret_cast<const float4*>(wz + FD + d);
                    float4 c4 = *reinterpret_cast<const float4*>(wr + FD + d);
                    float4 e4 = *reinterpret_cast<const float4*>(wh + FD + d);
                    az  += hv.x*a4.x + hv.y*a4.y + hv.z*a4.z + hv.w*a4.w;
                    ar  += hv.x*c4.x + hv.y*c4.y + hv.z*c4.z + hv.w*c4.w;
                    aoh += hv.x*e4.x + hv.y*e4.y + hv.z*e4.z + hv.w*e4.w;
                }
            }
        }
        __syncthreads();                               // all hl reads done
        if (valid && k == 1) {
            float* px = pxch + pairIdx * 5;
            px[0] = az; px[1] = ar; px[2] = aoh;
        }
        __syncthreads();
        if (valid && k == 0) {
            const float* px = pxch + pairIdx * 5;
            az  += px[0];
            ar  += px[1];
            aoh += px[2];
            float z  = 1.f / (1.f + __expf(-(az + bzz)));
            float r  = 1.f / (1.f + __expf(-(ar + brr)));
            float hh = tanhf(axh + bxh + r * (aoh + brh));
            float hnew = z * hold + (1.f - z) * hh;
            hout[(size_t)(bg + b) * FH + ug + j] = hnew;
        }

        // ---- group barrier: 32 blocks of this batch-chunk ----
        if (t + 1 < T_FEAT) {
            if (tid < 256) __threadfence();            // release h stores (agent scope)
            __syncthreads();                           // all fences done before arrive
            if (tid == 0) {
                __hip_atomic_fetch_add(ctr, 1u, __ATOMIC_RELAXED, __HIP_MEMORY_SCOPE_AGENT);
                const unsigned int target = (unsigned int)(t + 1) * FUC;
                while (__hip_atomic_load(ctr, __ATOMIC_RELAXED, __HIP_MEMORY_SCOPE_AGENT) < target)
                    __builtin_amdgcn_s_sleep(1);
                __threadfence();                       // acquire remote h stores
            }
            __syncthreads();
        }
    }
}

// ---------------------------------------------------------------------------
// One GRU timestep, launch-per-step (used for the char branch only).
// ---------------------------------------------------------------------------
template<int D, int XPAD, int H, int UJ, int TB>
__launch_bounds__(256)
__global__ void gru_step(const float* __restrict__ xsrc,
                         const int*   __restrict__ ids,
                         int t, int Tlen,
                         const float* __restrict__ WT,
                         const float* __restrict__ b0,
                         const float* __restrict__ b1,
                         const float* __restrict__ hin,
                         float*       __restrict__ hout)
{
    constexpr int DHp  = XPAD + H;
    constexpr int LDSP = DHp + 4;
    __shared__ float xh[TB][LDSP];

    const int tid = threadIdx.x;
    const int nj  = H / UJ;
    const int bc  = blockIdx.x / nj;
    const int jc  = blockIdx.x % nj;
    const int bg  = bc * TB;

    if (ids == nullptr) {
        constexpr int XV = D / 4;
        for (int i = tid; i < TB * XV; i += blockDim.x) {
            int b = i / XV, v = i % XV;
            float4 val = *reinterpret_cast<const float4*>(
                xsrc + ((size_t)(bg + b) * Tlen + t) * D + v * 4);
            *reinterpret_cast<float4*>(&xh[b][v * 4]) = val;
        }
    } else {
        constexpr int XV2 = D / 2;
        for (int i = tid; i < TB * XV2; i += blockDim.x) {
            int b = i / XV2, v = i % XV2;
            int id = ids[(size_t)(bg + b) * Tlen + t];
            float2 val = *reinterpret_cast<const float2*>(xsrc + (size_t)id * D + v * 2);
            xh[b][v * 2]     = val.x;
            xh[b][v * 2 + 1] = val.y;
        }
        if constexpr (XPAD > D) {
            for (int i = tid; i < TB * (XPAD - D); i += blockDim.x) {
                int b = i / (XPAD - D), v = i % (XPAD - D);
                xh[b][D + v] = 0.f;
            }
        }
    }
    {
        constexpr int HV = H / 4;
        for (int i = tid; i < TB * HV; i += blockDim.x) {
            int b = i / HV, v = i % HV;
            float4 val = *reinterpret_cast<const float4*>(
                hin + (size_t)(bg + b) * H + v * 4);
            *reinterpret_cast<float4*>(&xh[b][XPAD + v * 4]) = val;
        }
    }
    __syncthreads();

    if (tid < TB * UJ) {
        const int j  = tid % UJ;
        const int b  = tid / UJ;
        const int jj = jc * UJ + j;

        const float* __restrict__ wz = WT + (size_t)jj * DHp;
        const float* __restrict__ wr = WT + (size_t)(H + jj) * DHp;
        const float* __restrict__ wh = WT + (size_t)(2 * H + jj) * DHp;
        const float* __restrict__ xrow = xh[b];

        float az = 0.f, ar = 0.f, axh = 0.f, arh = 0.f;

        #pragma unroll 4
        for (int d = 0; d < XPAD; d += 4) {
            float4 xv = *reinterpret_cast<const float4*>(&xrow[d]);
            float4 z4 = *reinterpret_cast<const float4*>(wz + d);
            float4 r4 = *reinterpret_cast<const float4*>(wr + d);
            float4 h4 = *reinterpret_cast<const float4*>(wh + d);
            az  += xv.x * z4.x + xv.y * z4.y + xv.z * z4.z + xv.w * z4.w;
            ar  += xv.x * r4.x + xv.y * r4.y + xv.z * r4.z + xv.w * r4.w;
            axh += xv.x * h4.x + xv.y * h4.y + xv.z * h4.z + xv.w * h4.w;
        }
        #pragma unroll 4
        for (int d = XPAD; d < DHp; d += 4) {
            float4 xv = *reinterpret_cast<const float4*>(&xrow[d]);
            float4 z4 = *reinterpret_cast<const float4*>(wz + d);
            float4 r4 = *reinterpret_cast<const float4*>(wr + d);
            float4 h4 = *reinterpret_cast<const float4*>(wh + d);
            az  += xv.x * z4.x + xv.y * z4.y + xv.z * z4.z + xv.w * z4.w;
            ar  += xv.x * r4.x + xv.y * r4.y + xv.z * r4.z + xv.w * r4.w;
            arh += xv.x * h4.x + xv.y * h4.y + xv.z * h4.z + xv.w * h4.w;
        }

        float z = 1.f / (1.f + __expf(-(az + b0[jj] + b1[jj])));
        float r = 1.f / (1.f + __expf(-(ar + b0[H + jj] + b1[H + jj])));
        float hh = tanhf(axh + b0[2 * H + jj] + r * (arh + b1[2 * H + jj]));
        float hold = xrow[XPAD + jj];
        float hnew = z * hold + (1.f - z) * hh;
        hout[(size_t)(bg + b) * H + jj] = hnew;
    }
}

// ---------------------------------------------------------------------------
// dense: y[row] = act(x[row] @ W + bias). ACT: 0 none, 1 relu, 2 softmax
// ---------------------------------------------------------------------------
template<int ACT>
__launch_bounds__(256)
__global__ void dense(const float* __restrict__ x, int ldx, int D,
                      const float* __restrict__ W, const float* __restrict__ bias, int N,
                      float* __restrict__ y, int ldy)
{
    __shared__ float xs[544];
    __shared__ float ys[288];
    __shared__ float red[2];
    const int row = blockIdx.x;
    const float* xr = x + (size_t)row * ldx;
    for (int i = threadIdx.x; i < D; i += blockDim.x) xs[i] = xr[i];
    __syncthreads();
    for (int j = threadIdx.x; j < N; j += blockDim.x) {
        float acc = bias[j];
        for (int d = 0; d < D; ++d) acc += xs[d] * W[(size_t)d * N + j];
        if (ACT == 1) acc = fmaxf(acc, 0.f);
        if (ACT == 2) ys[j] = acc;
        else          y[(size_t)row * ldy + j] = acc;
    }
    if (ACT == 2) {
        __syncthreads();
        if (threadIdx.x == 0) {
            float m = -1e30f;
            for (int i = 0; i < N; ++i) m = fmaxf(m, ys[i]);
            float s = 0.f;
            for (int i = 0; i < N; ++i) s += expf(ys[i] - m);
            red[0] = m; red[1] = s;
        }
        __syncthreads();
        float m = red[0], s = red[1];
        for (int j = threadIdx.x; j < N; j += blockDim.x)
            y[(size_t)row * ldy + j] = expf(ys[j] - m) / s;
    }
}

// ---------------------------------------------------------------------------
extern "C" void kernel_launch(void* const* d_in, const int* in_sizes, int n_in,
                              void* d_out, int out_size, void* d_ws, size_t ws_size,
                              hipStream_t stream)
{
    const float* feat = (const float*)d_in[1];
    const int*   cids = (const int*)  d_in[2];
    const float* emb  = (const float*)d_in[3];
    const float* Wc   = (const float*)d_in[4];
    const float* Uc   = (const float*)d_in[5];
    const float* bcb  = (const float*)d_in[6];
    const float* Wf   = (const float*)d_in[7];
    const float* Uf   = (const float*)d_in[8];
    const float* bfb  = (const float*)d_in[9];
    const float* Wfd  = (const float*)d_in[10]; const float* bfd = (const float*)d_in[11];
    const float* Wc1  = (const float*)d_in[12]; const float* bc1 = (const float*)d_in[13];
    const float* Wc2  = (const float*)d_in[14]; const float* bc2 = (const float*)d_in[15];
    const float* W1   = (const float*)d_in[16]; const float* b1  = (const float*)d_in[17];
    const float* W2   = (const float*)d_in[18]; const float* b2  = (const float*)d_in[19];
    const float* Wsm  = (const float*)d_in[20]; const float* bsm = (const float*)d_in[21];
    float* out = (float*)d_out;

    // workspace carve-up (floats), ~3.6 MB total
    float* ws  = (float*)d_ws;
    float* WTf = ws; ws += 768 * 384;
    float* WTc = ws; ws += 600 * 352;
    float* hf0 = ws; ws += BATCH * H_FEAT;
    float* hf1 = ws; ws += BATCH * H_FEAT;
    float* hc0 = ws; ws += BATCH * H_CHAR;
    float* hc1 = ws; ws += BATCH * H_CHAR;
    float* xcat = ws; ws += BATCH * (2 * HID);
    float* tA  = ws; ws += BATCH * HID;
    float* tB  = ws; ws += BATCH * HID;
    unsigned int* ctrs = (unsigned int*)ws;          // FBC*64 uints

    hipMemsetAsync(hf0, 0, BATCH * H_FEAT * sizeof(float), stream);
    hipMemsetAsync(hc0, 0, BATCH * H_CHAR * sizeof(float), stream);
    hipMemsetAsync(ctrs, 0, FBC * 64 * sizeof(unsigned int), stream);

    {
        int tot_f = 768 * 384;
        prep_wt<<<(tot_f + 255) / 256, 256, 0, stream>>>(Wf, Uf, WTf, 128, 128, H_FEAT);
        int tot_c = 600 * 352;
        prep_wt<<<(tot_c + 255) / 256, 256, 0, stream>>>(Wc, Uc, WTc, 150, 152, H_CHAR);
    }

    // ---- char GRU: 128 per-step launches ----
    {
        float* hb[2] = {hc0, hc1};
        for (int t = 0; t < T_CHAR; ++t) {
            gru_step<150, 152, H_CHAR, 8, 25>
                <<<dim3((BATCH / 25) * (H_CHAR / 8)), 256, 0, stream>>>(
                    emb, cids, t, T_CHAR, WTc, bcb, bcb + 600, hb[t & 1], hb[(t + 1) & 1]);
        }
    }

    // ---- feature GRU: one persistent cooperative launch ----
    {
        const float* b0f = bfb;
        const float* b1f = bfb + 3 * H_FEAT;
        void* args[] = { (void*)&feat, (void*)&WTf, (void*)&b0f, (void*)&b1f,
                         (void*)&hf0, (void*)&hf1, (void*)&ctrs };
        hipLaunchCooperativeKernel((void*)gru_feat_persist,
                                   dim3(FBC * FUC), dim3(512), args, 0, stream);
    }

    // ---- heads ----
    dense<1><<<BATCH, 256, 0, stream>>>(hf0, H_FEAT, H_FEAT, Wfd, bfd, HID, xcat,       2 * HID);
    dense<1><<<BATCH, 256, 0, stream>>>(hc0, H_CHAR, H_CHAR, Wc1, bc1, HID, tA,         HID);
    dense<2><<<BATCH, 256, 0, stream>>>(tA,  HID,    HID,    Wc2, bc2, HID, xcat + HID, 2 * HID);
    dense<1><<<BATCH, 256, 0, stream>>>(xcat, 2 * HID, 2 * HID, W1, b1, HID, tB,        HID);
    dense<1><<<BATCH, 256, 0, stream>>>(tB,  HID,    HID,    W2,  b2,  HID, tA,         HID);
    dense<2><<<BATCH, 256, 0, stream>>>(tA,  HID,    HID,    Wsm, bsm, NCLS, out,       NCLS);
}

// Round 3
// 44628.049 us; speedup vs baseline: 1.5734x; 1.5734x over previous
//
#include <hip/hip_runtime.h>
#include <hip/hip_bf16.h>
#include <math.h>

// ---------------- problem constants ----------------
#define BATCH 200
#define T_FEAT 2048
#define F_DIM 128
#define T_CHAR 128
#define EMB_D 150
#define VOCAB 5000
#define H_FEAT 256
#define H_CHAR 200
#define HID 264
#define NCLS 8

// ---------------- persistent GRU geometry ----------------
#define TB 25            // batch rows per group (and per block)
#define UJ 8             // h-units per block
#define NGRP 8           // batch groups (BATCH / TB)
#define FLAG_STRIDE 16   // uints between flags (64 B -> no line contention)

// ---------------------------------------------------------------------------
// prep: fused+transposed recurrent weights WT[3H][XPAD+H]
//   row c (= gate-column index in [0,3H)) = [ W[0:D,c] | 0 | U[0:H,c] ]
// ---------------------------------------------------------------------------
__global__ void prep_wt(const float* __restrict__ W, const float* __restrict__ U,
                        float* __restrict__ WT, int D, int XPAD, int H)
{
    const int DHp = XPAD + H;
    const int total = 3 * H * DHp;
    int idx = blockIdx.x * blockDim.x + threadIdx.x;
    if (idx >= total) return;
    int c = idx / DHp;
    int d = idx % DHp;
    float v;
    if (d < D)          v = W[(size_t)d * (3 * H) + c];
    else if (d < XPAD)  v = 0.f;
    else                v = U[(size_t)(d - XPAD) * (3 * H) + c];
    WT[idx] = v;
}

// pad emb table to 152 cols (zeros) so K-loops are clean float4
__global__ void prep_emb(const float* __restrict__ emb, float* __restrict__ embP)
{
    int idx = blockIdx.x * blockDim.x + threadIdx.x;
    const int total = VOCAB * 152;
    if (idx >= total) return;
    int v = idx / 152, d = idx % 152;
    embP[idx] = (d < EMB_D) ? emb[(size_t)v * EMB_D + d] : 0.f;
}

// ---------------------------------------------------------------------------
// Persistent GRU (cooperative). Group = NBPG blocks sharing TB batch rows;
// each block owns UJ h-units. Per step:
//   poll flags (wave0, agent loads) -> acquire fence (inv only, NO wbl2)
//   -> h-dots (normal dwordx4 global h reads, LDS weights)
//   -> LDS partial exchange -> gates (k=0) -> agent-scope h stores
//   -> __syncthreads (vmcnt drain) -> per-block flag store (agent).
// x-dot partials for step t+1 are computed after the flag store, hidden in
// the flag-propagation window (they don't depend on h).
// ---------------------------------------------------------------------------
template<int XPAD, int H, int T, bool EMBED, int NBPG, int WS>
__launch_bounds__(512)
__global__ void gru_persist(const float* __restrict__ xsrc,   // feat or embP
                            const int*   __restrict__ ids,    // char ids or null
                            const float* __restrict__ WT,     // [3H][XPAD+H]
                            const float* __restrict__ bias0,  // input bias
                            const float* __restrict__ bias1,  // recurrent bias
                            float* __restrict__ hA,           // [BATCH][H] zeroed
                            float* __restrict__ hB,
                            unsigned* __restrict__ flags)     // zeroed
{
    constexpr int DHp = XPAD + H;
    constexpr int XH  = XPAD / 2;     // x K-split half (64 / 76)
    constexpr int HH  = H / 2;        // h K-split half (128 / 100)
    __shared__ float w[3 * UJ][WS];   // weight slice, reused all T steps
    __shared__ float px[256 * 5];     // partial exchange (stride 5: no conflicts)

    const int tid = threadIdx.x;
    const int bc  = blockIdx.x % NGRP;     // group (same XCD under round-robin)
    const int uc  = blockIdx.x / NGRP;     // unit chunk within group
    const int bg  = bc * TB;
    const int ug  = uc * UJ;

    // ---- stage this block's weight slice once ----
    for (int i = tid; i < 3 * UJ * (DHp / 4); i += 512) {
        int r  = i / (DHp / 4);
        int d4 = (i % (DHp / 4)) * 4;
        int wrow = (r >> 3) * H + ug + (r & 7);   // gate*H + unit
        *reinterpret_cast<float4*>(&w[r][d4]) =
            *reinterpret_cast<const float4*>(WT + (size_t)wrow * DHp + d4);
    }

    const int k = tid >> 8;            // K-split half (waves 0-3 / 4-7)
    const int pairIdx = tid & 255;
    const int j = pairIdx & 7;         // unit within block
    const int b = pairIdx >> 3;        // batch row within group
    const bool valid = (b < TB);

    const float bzz = bias0[ug + j] + bias1[ug + j];
    const float brr = bias0[H + ug + j] + bias1[H + ug + j];
    const float bxh = bias0[2 * H + ug + j];
    const float brh = bias1[2 * H + ug + j];

    unsigned* gflags = flags + (size_t)bc * 32 * FLAG_STRIDE;
    unsigned* myflag = gflags + (size_t)uc * FLAG_STRIDE;

    float hold = 0.f;                  // this (b,unit)'s running h (k=0 only)
    float xaz = 0.f, xar = 0.f, xah = 0.f;

    __syncthreads();                   // weights staged

    // ---- x-dot partials for t=0 ----
    if (valid) {
        const float* xrow;
        if constexpr (EMBED) {
            int id = ids[(size_t)(bg + b) * T + 0];
            xrow = xsrc + (size_t)id * XPAD + k * XH;
        } else {
            xrow = xsrc + ((size_t)(bg + b) * T + 0) * XPAD + k * XH;
        }
        const float* wz = &w[j][k * XH];
        const float* wr = &w[UJ + j][k * XH];
        const float* wh = &w[2 * UJ + j][k * XH];
        #pragma unroll 4
        for (int d = 0; d < XH; d += 4) {
            float4 xv = *reinterpret_cast<const float4*>(xrow + d);
            float4 a4 = *reinterpret_cast<const float4*>(wz + d);
            float4 c4 = *reinterpret_cast<const float4*>(wr + d);
            float4 e4 = *reinterpret_cast<const float4*>(wh + d);
            xaz += xv.x*a4.x + xv.y*a4.y + xv.z*a4.z + xv.w*a4.w;
            xar += xv.x*c4.x + xv.y*c4.y + xv.z*c4.z + xv.w*c4.w;
            xah += xv.x*e4.x + xv.y*e4.y + xv.z*e4.z + xv.w*e4.w;
        }
    }

    for (int t = 0; t < T; ++t) {
        const float* hin  = (t & 1) ? hB : hA;
        float*       hout = (t & 1) ? hA : hB;

        // ---- wait for h(t) ----
        if (t > 0) {
            if (tid < 64) {
                const unsigned tgt = (unsigned)t;
                unsigned* fp = gflags + (size_t)tid * FLAG_STRIDE;
                const bool need = (tid < NBPG);
                for (;;) {
                    unsigned v = need ? __hip_atomic_load(fp, __ATOMIC_RELAXED,
                                                          __HIP_MEMORY_SCOPE_AGENT)
                                      : tgt;
                    if (__all((int)(v >= tgt))) break;
                }
            }
            __syncthreads();
            // acquire: invalidate-only (no L2 writeback), per wave
            __builtin_amdgcn_fence(__ATOMIC_ACQUIRE, "agent");
        }

        // ---- h-dots over this half's K range (normal cached loads) ----
        float haz = 0.f, har = 0.f, hah = 0.f;
        if (valid) {
            const float* hrow = hin + (size_t)(bg + b) * H + k * HH;
            const float* wz = &w[j][XPAD + k * HH];
            const float* wr = &w[UJ + j][XPAD + k * HH];
            const float* wh = &w[2 * UJ + j][XPAD + k * HH];
            #pragma unroll 4
            for (int d = 0; d < HH; d += 4) {
                float4 hv = *reinterpret_cast<const float4*>(hrow + d);
                float4 a4 = *reinterpret_cast<const float4*>(wz + d);
                float4 c4 = *reinterpret_cast<const float4*>(wr + d);
                float4 e4 = *reinterpret_cast<const float4*>(wh + d);
                haz += hv.x*a4.x + hv.y*a4.y + hv.z*a4.z + hv.w*a4.w;
                har += hv.x*c4.x + hv.y*c4.y + hv.z*c4.z + hv.w*c4.w;
                hah += hv.x*e4.x + hv.y*e4.y + hv.z*e4.z + hv.w*e4.w;
            }
        }

        // ---- exchange k=1 partials via LDS ----
        const float az_h = xaz + haz;      // z-gate: x and h parts merge
        const float ar_h = xar + har;
        if (valid && k == 1) {
            float* p = &px[pairIdx * 5];
            p[0] = az_h; p[1] = ar_h; p[2] = xah; p[3] = hah;
        }
        __syncthreads();
        if (valid && k == 0) {
            const float* p = &px[pairIdx * 5];
            float az = az_h + p[0];
            float ar = ar_h + p[1];
            float xh_t = xah + p[2];        // x·Wh (outside r)
            float rh_t = hah + p[3];        // h·Uh (inside r)
            float z = 1.f / (1.f + __expf(-(az + bzz)));
            float r = 1.f / (1.f + __expf(-(ar + brr)));
            float hh = tanhf(xh_t + bxh + r * (rh_t + brh));
            float hnew = z * hold + (1.f - z) * hh;
            hold = hnew;
            // agent-scope write-through store: visible at coherence point, no wbl2
            __hip_atomic_store(hout + (size_t)(bg + b) * H + ug + j, hnew,
                               __ATOMIC_RELAXED, __HIP_MEMORY_SCOPE_AGENT);
        }
        __syncthreads();   // compiler drains vmcnt(0) before s_barrier -> stores done
        if (tid == 0 && t + 1 < T)
            __hip_atomic_store(myflag, (unsigned)(t + 1),
                               __ATOMIC_RELAXED, __HIP_MEMORY_SCOPE_AGENT);

        // ---- x-dot partials for t+1, hidden in flag-propagation window ----
        xaz = xar = xah = 0.f;
        if (valid && t + 1 < T) {
            const float* xrow;
            if constexpr (EMBED) {
                int id = ids[(size_t)(bg + b) * T + (t + 1)];
                xrow = xsrc + (size_t)id * XPAD + k * XH;
            } else {
                xrow = xsrc + ((size_t)(bg + b) * T + (t + 1)) * XPAD + k * XH;
            }
            const float* wz = &w[j][k * XH];
            const float* wr = &w[UJ + j][k * XH];
            const float* wh = &w[2 * UJ + j][k * XH];
            #pragma unroll 4
            for (int d = 0; d < XH; d += 4) {
                float4 xv = *reinterpret_cast<const float4*>(xrow + d);
                float4 a4 = *reinterpret_cast<const float4*>(wz + d);
                float4 c4 = *reinterpret_cast<const float4*>(wr + d);
                float4 e4 = *reinterpret_cast<const float4*>(wh + d);
                xaz += xv.x*a4.x + xv.y*a4.y + xv.z*a4.z + xv.w*a4.w;
                xar += xv.x*c4.x + xv.y*c4.y + xv.z*c4.z + xv.w*c4.w;
                xah += xv.x*e4.x + xv.y*e4.y + xv.z*e4.z + xv.w*e4.w;
            }
        }
    }
}

// ---------------------------------------------------------------------------
// dense: y[row] = act(x[row] @ W + bias). ACT: 0 none, 1 relu, 2 softmax
// ---------------------------------------------------------------------------
template<int ACT>
__launch_bounds__(256)
__global__ void dense(const float* __restrict__ x, int ldx, int D,
                      const float* __restrict__ W, const float* __restrict__ bias, int N,
                      float* __restrict__ y, int ldy)
{
    __shared__ float xs[544];
    __shared__ float ys[288];
    __shared__ float red[2];
    const int row = blockIdx.x;
    const float* xr = x + (size_t)row * ldx;
    for (int i = threadIdx.x; i < D; i += blockDim.x) xs[i] = xr[i];
    __syncthreads();
    for (int j = threadIdx.x; j < N; j += blockDim.x) {
        float acc = bias[j];
        for (int d = 0; d < D; ++d) acc += xs[d] * W[(size_t)d * N + j];
        if (ACT == 1) acc = fmaxf(acc, 0.f);
        if (ACT == 2) ys[j] = acc;
        else          y[(size_t)row * ldy + j] = acc;
    }
    if (ACT == 2) {
        __syncthreads();
        if (threadIdx.x == 0) {
            float m = -1e30f;
            for (int i = 0; i < N; ++i) m = fmaxf(m, ys[i]);
            float s = 0.f;
            for (int i = 0; i < N; ++i) s += expf(ys[i] - m);
            red[0] = m; red[1] = s;
        }
        __syncthreads();
        float m = red[0], s = red[1];
        for (int j = threadIdx.x; j < N; j += blockDim.x)
            y[(size_t)row * ldy + j] = expf(ys[j] - m) / s;
    }
}

// ---------------------------------------------------------------------------
extern "C" void kernel_launch(void* const* d_in, const int* in_sizes, int n_in,
                              void* d_out, int out_size, void* d_ws, size_t ws_size,
                              hipStream_t stream)
{
    const float* feat = (const float*)d_in[1];
    const int*   cids = (const int*)  d_in[2];
    const float* emb  = (const float*)d_in[3];
    const float* Wc   = (const float*)d_in[4];
    const float* Uc   = (const float*)d_in[5];
    const float* bcb  = (const float*)d_in[6];
    const float* Wf   = (const float*)d_in[7];
    const float* Uf   = (const float*)d_in[8];
    const float* bfb  = (const float*)d_in[9];
    const float* Wfd  = (const float*)d_in[10]; const float* bfd = (const float*)d_in[11];
    const float* Wc1  = (const float*)d_in[12]; const float* bc1 = (const float*)d_in[13];
    const float* Wc2  = (const float*)d_in[14]; const float* bc2 = (const float*)d_in[15];
    const float* W1   = (const float*)d_in[16]; const float* b1  = (const float*)d_in[17];
    const float* W2   = (const float*)d_in[18]; const float* b2  = (const float*)d_in[19];
    const float* Wsm  = (const float*)d_in[20]; const float* bsm = (const float*)d_in[21];
    float* out = (float*)d_out;

    // workspace carve-up (floats), ~6.5 MB total
    float* ws  = (float*)d_ws;
    float* WTf = ws; ws += 768 * 384;            // feature fused weights
    float* WTc = ws; ws += 600 * 352;            // char fused weights
    float* embP = ws; ws += VOCAB * 152;         // padded emb table
    float* hf0 = ws; ws += BATCH * H_FEAT;
    float* hf1 = ws; ws += BATCH * H_FEAT;
    float* hc0 = ws; ws += BATCH * H_CHAR;
    float* hc1 = ws; ws += BATCH * H_CHAR;
    float* xcat = ws; ws += BATCH * (2 * HID);
    float* tA  = ws; ws += BATCH * HID;
    float* tB  = ws; ws += BATCH * HID;
    unsigned* flagsF = (unsigned*)ws; ws += NGRP * 32 * FLAG_STRIDE;  // (uints fit in floats)
    unsigned* flagsC = (unsigned*)ws; ws += NGRP * 32 * FLAG_STRIDE;

    hipMemsetAsync(hf0, 0, BATCH * H_FEAT * sizeof(float), stream);
    hipMemsetAsync(hc0, 0, BATCH * H_CHAR * sizeof(float), stream);
    hipMemsetAsync(flagsF, 0, NGRP * 32 * FLAG_STRIDE * sizeof(unsigned) * 2, stream);

    prep_wt<<<(768 * 384 + 255) / 256, 256, 0, stream>>>(Wf, Uf, WTf, 128, 128, H_FEAT);
    prep_wt<<<(600 * 352 + 255) / 256, 256, 0, stream>>>(Wc, Uc, WTc, 150, 152, H_CHAR);
    prep_emb<<<(VOCAB * 152 + 255) / 256, 256, 0, stream>>>(emb, embP);

    // ---- char GRU: persistent cooperative (200 blocks) ----
    {
        const float* b0c = bcb;
        const float* b1c = bcb + 3 * H_CHAR;
        void* args[] = { (void*)&embP, (void*)&cids, (void*)&WTc, (void*)&b0c,
                         (void*)&b1c, (void*)&hc0, (void*)&hc1, (void*)&flagsC };
        hipLaunchCooperativeKernel(
            (void*)gru_persist<152, H_CHAR, T_CHAR, true, 25, 356>,
            dim3(NGRP * 25), dim3(512), args, 0, stream);
    }
    // ---- feature GRU: persistent cooperative (256 blocks) ----
    {
        const int* nullids = nullptr;
        const float* b0f = bfb;
        const float* b1f = bfb + 3 * H_FEAT;
        void* args[] = { (void*)&feat, (void*)&nullids, (void*)&WTf, (void*)&b0f,
                         (void*)&b1f, (void*)&hf0, (void*)&hf1, (void*)&flagsF };
        hipLaunchCooperativeKernel(
            (void*)gru_persist<128, H_FEAT, T_FEAT, false, 32, 388>,
            dim3(NGRP * 32), dim3(512), args, 0, stream);
    }
    // both T even -> final states in buffer 0

    // ---- heads ----
    dense<1><<<BATCH, 256, 0, stream>>>(hf0, H_FEAT, H_FEAT, Wfd, bfd, HID, xcat,       2 * HID);
    dense<1><<<BATCH, 256, 0, stream>>>(hc0, H_CHAR, H_CHAR, Wc1, bc1, HID, tA,         HID);
    dense<2><<<BATCH, 256, 0, stream>>>(tA,  HID,    HID,    Wc2, bc2, HID, xcat + HID, 2 * HID);
    dense<1><<<BATCH, 256, 0, stream>>>(xcat, 2 * HID, 2 * HID, W1, b1, HID, tB,        HID);
    dense<1><<<BATCH, 256, 0, stream>>>(tB,  HID,    HID,    W2,  b2,  HID, tA,         HID);
    dense<2><<<BATCH, 256, 0, stream>>>(tA,  HID,    HID,    Wsm, bsm, NCLS, out,       NCLS);
}